// Round 4
// baseline (237.755 us; speedup 1.0000x reference)
//
#include <hip/hip_runtime.h>
#include <hip/hip_bf16.h>
#include <cstdint>

// Problem: out = x @ (W + scale*B@A)^T + b
//   x[4,2048,2048] -> X[M=8192, K=2048],  W[N=2048, K=2048], b[N],
//   A[R=16, K], B[N, R=16], scale scalar.  ALL I/O IS FLOAT32.
// R6: 256x256 8-phase GEMM, counted vmcnt -> 77us, MfmaUtil 36%.
// R7: faithful m201 cadence -> 75.4us, MfmaUtil 36%. Schedule axis exhausted.
// R8: fuse x fp32->bf16 into GEMM A-staging (reg-staged, T14 split). FAILED:
//     prologue staged A(mh1,kt0) into Sa[1][0] instead of A(mh0,kt1) —
//     row/col offset mixup (64*2048 vs 64). absmax 1.44 == one wrong K-tile.
// R9: fix that one line (AISSUE(0,1); AWRITE(1,0)). Schedule otherwise
//     identical to R8; liveness + FIFO-retirement re-audited.

typedef __bf16 bf16x8 __attribute__((ext_vector_type(8)));
typedef float floatx4 __attribute__((ext_vector_type(4)));
typedef unsigned short ushort8 __attribute__((ext_vector_type(8)));

#define BM 256
#define BN 256
#define BK 64
#define NT 32   // K / BK

__device__ __forceinline__ void gload_lds16(const void* g, void* l) {
    // 16B-per-lane async global->LDS. LDS dest must be wave-uniform base + lane*16.
    __builtin_amdgcn_global_load_lds((__attribute__((address_space(1))) void*)g,
                                     (__attribute__((address_space(3))) void*)l,
                                     16, 0, 0);
}

// fp32 -> bf16 bits, round-to-nearest-even (finite inputs only).
__device__ __forceinline__ unsigned short f2bf_bits(float f) {
    unsigned int u = __float_as_uint(f);
    u += 0x7FFFu + ((u >> 16) & 1u);
    return (unsigned short)(u >> 16);
}

// ---------------------------------------------------------------------------
// Aux kernel: Weff = bf16(W + scale*B@A) only. 2048 blocks.
// ---------------------------------------------------------------------------
__global__ __launch_bounds__(256)
void aux_kernel(const float* __restrict__ W, const float* __restrict__ A,
                const float* __restrict__ Bm, const float* __restrict__ scale_p,
                unsigned short* __restrict__ Weff)
{
    const int K = 2048, R = 16;
    int t  = blockIdx.x * 256 + threadIdx.x;
    int n  = t >> 8;
    int k8 = (t & 255) << 3;

    float s = *scale_p;
    float br[16];
#pragma unroll
    for (int r = 0; r < R; ++r)
        br[r] = s * Bm[n * R + r];

    float acc[8] = {0,0,0,0,0,0,0,0};
#pragma unroll
    for (int r = 0; r < R; ++r) {
        const float* ap = A + r * K + k8;
#pragma unroll
        for (int j = 0; j < 8; ++j)
            acc[j] += br[r] * ap[j];
    }

    const float* wp = W + (size_t)n * K + k8;
    ushort8 o;
#pragma unroll
    for (int j = 0; j < 8; ++j)
        o[j] = f2bf_bits(wp[j] + acc[j]);
    *reinterpret_cast<ushort8*>(Weff + (size_t)n * K + k8) = o;
}

// ---------------------------------------------------------------------------
// GEMM: out[M,N] (fp32) = bf16(x)[M,K] @ Weffbf[N,K]^T + bias (fp32)
//
// LDS regions (16 KB each, 128 KiB total):
//   Sa[buf][mh]: A M-half [wrH(2)][64 r][64 c bf16], rows bm+wrH*128+mh*64+r.
//                Written by ds_write_b128 (reg-staged fp32->bf16), swizzled
//                on the WRITE: 16B slot s -> s ^ (r&7).
//   Sb[buf][nh]: B N-half [wcH(4)][32 r][64 c], rows bn+wcH*64+nh*32+r.
//                Written by global_load_lds (linear dest, pre-swizzled src).
// Read side uses the same involution (slot ^ (row&7)); measured 0 conflicts.
//
// 8 phases / 2 K-tiles, Gray quadrant order (m0n0, m0n1, m1n1, m1n0).
// Steady-state slots (hand-verified liveness + FIFO-retirement):
//   P1: issue B-gl Sb[1][0]<-t1;  issue A-loads (mh1,t1)
//   P2: cvt+write Sa[1][1];       issue A-loads (mh0,t2)
//   P3: cvt+write Sa[0][0]
//   P4: issue B-gl Sb[0][1]<-t2
//   P5: issue B-gl Sb[0][0]<-t2;  issue A-loads (mh1,t2)
//   P6: cvt+write Sa[0][1];       issue A-loads (mh0,t3)
//   P7: cvt+write Sa[1][0]
//   P8: issue B-gl Sb[1][1]<-t3
// Every B region's first read is preceded by a compiler vmcnt wait for a
// NEWER A-load set (FIFO => B retired). No manual loop vmcnt needed.
// ---------------------------------------------------------------------------
#define BAR()       __builtin_amdgcn_s_barrier()
#define WAIT_LGKM() asm volatile("s_waitcnt lgkmcnt(0)" ::: "memory")
#define WAIT_VM0()  asm volatile("s_waitcnt vmcnt(0)" ::: "memory")

#define STAGE_B(buf, nh, kt) do {                                             \
    gload_lds16(gB0 + (size_t)(nh) * 32 * 2048 + (kt) * 64, &Sb[buf][nh][c0 * 8]); \
    gload_lds16(gB1 + (size_t)(nh) * 32 * 2048 + (kt) * 64, &Sb[buf][nh][c1 * 8]); \
} while (0)

// Issue 16 fp32 x-loads for A-region (mh) of K-tile kt (consumed next phase).
#define AISSUE(mh, kt) do {                                                   \
    const float* xp = xA + (size_t)(mh) * 64 * 2048 + (kt) * 64;              \
    q0 = *reinterpret_cast<const float4*>(xp);                                \
    q1 = *reinterpret_cast<const float4*>(xp + 4);                            \
    q2 = *reinterpret_cast<const float4*>(xp + 128 * 2048);                   \
    q3 = *reinterpret_cast<const float4*>(xp + 128 * 2048 + 4);               \
} while (0)

// Convert + swizzled ds_write of the in-flight A set.
#define AWRITE(buf, mh) do {                                                  \
    ushort8 o0, o1;                                                           \
    o0[0]=f2bf_bits(q0.x); o0[1]=f2bf_bits(q0.y); o0[2]=f2bf_bits(q0.z);      \
    o0[3]=f2bf_bits(q0.w); o0[4]=f2bf_bits(q1.x); o0[5]=f2bf_bits(q1.y);      \
    o0[6]=f2bf_bits(q1.z); o0[7]=f2bf_bits(q1.w);                             \
    o1[0]=f2bf_bits(q2.x); o1[1]=f2bf_bits(q2.y); o1[2]=f2bf_bits(q2.z);      \
    o1[3]=f2bf_bits(q2.w); o1[4]=f2bf_bits(q3.x); o1[5]=f2bf_bits(q3.y);      \
    o1[6]=f2bf_bits(q3.z); o1[7]=f2bf_bits(q3.w);                             \
    *reinterpret_cast<ushort8*>(&Sa[buf][mh][dstA])        = o0;              \
    *reinterpret_cast<ushort8*>(&Sa[buf][mh][dstA + 4096]) = o1;              \
} while (0)

#define READ_A(buf, mh) do {                                                  \
    const unsigned short* ra = &Sa[buf][mh][(wr * 64 + lrow) * 64];           \
    _Pragma("unroll")                                                         \
    for (int mq = 0; mq < 4; ++mq) {                                          \
        af[0][mq] = *reinterpret_cast<const bf16x8*>(ra + mq * 1024 + swz0);  \
        af[1][mq] = *reinterpret_cast<const bf16x8*>(ra + mq * 1024 + swz1);  \
    }                                                                         \
} while (0)

#define READ_B(buf, nh) do {                                                  \
    const unsigned short* rb = &Sb[buf][nh][(wc * 32 + lrow) * 64];           \
    _Pragma("unroll")                                                         \
    for (int nq = 0; nq < 2; ++nq) {                                          \
        bq[0][nq] = *reinterpret_cast<const bf16x8*>(rb + nq * 1024 + swz0);  \
        bq[1][nq] = *reinterpret_cast<const bf16x8*>(rb + nq * 1024 + swz1);  \
    }                                                                         \
} while (0)

#define MFMAQ(mh, nh) do {                                                    \
    __builtin_amdgcn_s_setprio(1);                                            \
    _Pragma("unroll")                                                         \
    for (int mq = 0; mq < 4; ++mq)                                            \
        _Pragma("unroll")                                                     \
        for (int nq = 0; nq < 2; ++nq) {                                      \
            floatx4 tmp = __builtin_amdgcn_mfma_f32_16x16x32_bf16(            \
                af[0][mq], bq[0][nq], acc[(mh)*4+mq][(nh)*2+nq], 0, 0, 0);    \
            acc[(mh)*4+mq][(nh)*2+nq] = __builtin_amdgcn_mfma_f32_16x16x32_bf16( \
                af[1][mq], bq[1][nq], tmp, 0, 0, 0);                          \
        }                                                                     \
    __builtin_amdgcn_s_setprio(0);                                            \
} while (0)

__global__ __launch_bounds__(512, 2)
void gemm_bias_kernel(const float* __restrict__ x,
                      const unsigned short* __restrict__ Wt,
                      const float* __restrict__ bias,
                      float* __restrict__ out)
{
    const int N = 2048, K = 2048;

    __shared__ alignas(16) unsigned short Sa[2][2][8192];   // 64 KB
    __shared__ alignas(16) unsigned short Sb[2][2][8192];   // 64 KB

    const int tid  = threadIdx.x;
    const int wave = tid >> 6;
    const int lane = tid & 63;
    const int lrow = lane & 15;
    const int quad = lane >> 4;
    const int wr   = wave >> 2;   // 0..1  (M split)
    const int wc   = wave & 3;    // 0..3  (N split)

    // XCD-rectangle swizzle (bijective, 256 % 8 == 0).
    const int id  = blockIdx.x;            // 0..255
    const int xcd = id & 7;
    const int sg  = id >> 3;               // 0..31
    const int bm  = (xcd * 4 + (sg & 3)) * BM;
    const int bn  = (sg >> 2) * BN;

    // --- A staging geometry (reg-staged). Granules c0=tid (wrH0), c1=tid+512
    // (wrH1): same r,s. Global fp32 source LINEAR; LDS write swizzled.
    const int ar = (tid >> 3) & 63;               // region row 0..63
    const int as = tid & 7;                       // logical 16B slot
    const float* xA = x + (size_t)(bm + ar) * K + as * 8;
    const int dstA = ar * 64 + ((as ^ (ar & 7)) << 3);   // ushort offset
    float4 q0, q1, q2, q3;                        // in-flight A set

    // --- B staging geometry (global_load_lds, pre-swizzled source).
    const int c0 = tid, c1 = tid + 512;
    const int br0 = (c0 >> 3) & 31, br1 = (c1 >> 3) & 31;
    const unsigned short* gB0 = Wt + (size_t)(bn + (c0 >> 8) * 64 + br0) * K
                                   + ((as ^ (br0 & 7)) << 3);
    const unsigned short* gB1 = Wt + (size_t)(bn + (c1 >> 8) * 64 + br1) * K
                                   + (((c1 & 7) ^ (br1 & 7)) << 3);

    // ds_read swizzle: logical granule g = ks*4+quad, phys = g^(lrow&7).
    const int swz0 = (quad ^ (lrow & 7)) << 3;
    const int swz1 = swz0 ^ 32;

    floatx4 acc[8][4] = {};
    bf16x8 af[2][4];
    bf16x8 bq[2][2];

    // Prologue: tile0 A (both halves) + tile1 A-mh0; tile0 B (both) +
    // tile1 B-n1 via gload. Then full drain + barrier.
    STAGE_B(0, 0, 0);
    STAGE_B(0, 1, 0);
    STAGE_B(1, 1, 1);
    AISSUE(0, 0); AWRITE(0, 0);    // Sa[0][0] <- A mh0, tile0
    AISSUE(1, 0); AWRITE(0, 1);    // Sa[0][1] <- A mh1, tile0
    AISSUE(0, 1); AWRITE(1, 0);    // Sa[1][0] <- A mh0, tile1  (R8 bug fixed)
    WAIT_VM0(); WAIT_LGKM(); BAR();

#pragma unroll 1
    for (int tt = 0; tt < NT; tt += 2) {
        const int t1 = tt + 1;
        const int t2 = (tt + 2 < NT) ? tt + 2 : NT - 1;   // clamped tail
        const int t3 = (tt + 3 < NT) ? tt + 3 : NT - 1;   // (dead regions)

        // ---- tile t (buf0) ----
        // P1 (m0,n0)
        READ_A(0, 0); READ_B(0, 0);
        STAGE_B(1, 0, t1);
        AISSUE(1, t1);
        BAR(); WAIT_LGKM(); MFMAQ(0, 0); BAR();
        // P2 (m0,n1)
        AWRITE(1, 1);
        READ_B(0, 1);
        AISSUE(0, t2);
        BAR(); WAIT_LGKM(); MFMAQ(0, 1); BAR();
        // P3 (m1,n1)
        AWRITE(0, 0);
        READ_A(0, 1);
        BAR(); WAIT_LGKM(); MFMAQ(1, 1); BAR();
        // P4 (m1,n0)
        READ_B(0, 0);
        STAGE_B(0, 1, t2);
        BAR(); WAIT_LGKM(); MFMAQ(1, 0); BAR();

        // ---- tile t+1 (buf1) ----
        // P5 (m0,n0)
        READ_A(1, 0); READ_B(1, 0);
        STAGE_B(0, 0, t2);
        AISSUE(1, t2);   // A mh1 of tile t2 -> Sa[0][1]
        BAR(); WAIT_LGKM(); MFMAQ(0, 0); BAR();
        // P6 (m0,n1)
        AWRITE(0, 1);
        READ_B(1, 1);
        AISSUE(0, t3);   // A mh0 of tile t3 -> Sa[1][0]
        BAR(); WAIT_LGKM(); MFMAQ(0, 1); BAR();
        // P7 (m1,n1)
        AWRITE(1, 0);
        READ_A(1, 1);
        BAR(); WAIT_LGKM(); MFMAQ(1, 1); BAR();
        // P8 (m1,n0)
        READ_B(1, 0);
        STAGE_B(1, 1, t3);
        BAR(); WAIT_LGKM(); MFMAQ(1, 0); BAR();
    }
    WAIT_VM0();   // drain tail B-gloads before epilogue stores

    // Epilogue. C/D layout (m89/m91): col = lane&15, row = (lane>>4)*4 + reg.
    float bsv[4];
#pragma unroll
    for (int ni = 0; ni < 4; ++ni)
        bsv[ni] = bias[bn + wc * 64 + (ni >> 1) * 32 + (ni & 1) * 16 + lrow];

    const int rbase = quad << 2;
#pragma unroll
    for (int mi = 0; mi < 8; ++mi) {
#pragma unroll
        for (int r = 0; r < 4; ++r) {
            size_t rowoff = (size_t)(bm + wr * 128 + (mi >> 2) * 64
                                     + (mi & 3) * 16 + rbase + r) * N;
#pragma unroll
            for (int ni = 0; ni < 4; ++ni)
                out[rowoff + bn + wc * 64 + (ni >> 1) * 32 + (ni & 1) * 16 + lrow]
                    = acc[mi][ni][r] + bsv[ni];
        }
    }
}

extern "C" void kernel_launch(void* const* d_in, const int* in_sizes, int n_in,
                              void* d_out, int out_size, void* d_ws, size_t ws_size,
                              hipStream_t stream)
{
    const float* x  = (const float*)d_in[0];
    const float* W  = (const float*)d_in[1];
    const float* b  = (const float*)d_in[2];
    const float* A  = (const float*)d_in[3];
    const float* Bm = (const float*)d_in[4];
    const float* sc = (const float*)d_in[5];
    float* out = (float*)d_out;

    const size_t M = 8192, N = 2048, K = 2048;

    unsigned short* Weff = (unsigned short*)d_ws;   // 8 MB

    // 1) Weff = bf16(W + scale * B@A)   (2048 blocks, ~24 MB traffic)
    aux_kernel<<<dim3(N * K / 8 / 256), dim3(256), 0, stream>>>(
        W, A, Bm, sc, Weff);

    // 2) out = bf16(x) @ Weff^T + b  (fused cvt in A-staging)
    gemm_bias_kernel<<<dim3((M / BM) * (N / BN)), dim3(512), 0, stream>>>(
        x, Weff, b, out);
}

// Round 5
// 210.357 us; speedup vs baseline: 1.1302x; 1.1302x over previous
//
#include <hip/hip_runtime.h>
#include <hip/hip_bf16.h>
#include <cstdint>

// Problem: out = x @ (W + scale*B@A)^T + b
//   x[4,2048,2048] -> X[M=8192, K=2048],  W[N=2048, K=2048], b[N],
//   A[R=16, K], B[N, R=16], scale scalar.  ALL I/O IS FLOAT32.
// R6: 256x256 8-phase GEMM, counted vmcnt -> 77us, MfmaUtil 36%.
// R7: faithful m201 cadence -> 75.4us GEMM, 207.5 total (best known).
// R8/R9: A-fusion into GEMM -> fail / 126us. Axis reverted: 1-phase lead
//     can't hide x-load latency; per-phase vmcnt stall serialized all waves.
// R10: R7 base (aux = fused x-cvt + Weff; A/B via global_load_lds) with the
//     MFMA switched 16x16x32 -> 32x32x16 (2382 vs 2075 TF ubench, -13%
//     matrix-pipe cycles, 8 instead of 16 MFMA/phase) + separate bqa/bqb
//     registers so P4/P8 issue ZERO ds_reads (kills R7's B re-read).
//     Staging slots / vmcnt(4)@P4,P8 / barriers / swizzle: R7 verbatim.

typedef __bf16 bf16x8 __attribute__((ext_vector_type(8)));
typedef float floatx16 __attribute__((ext_vector_type(16)));
typedef unsigned short ushort8 __attribute__((ext_vector_type(8)));

#define BM 256
#define BN 256
#define BK 64
#define NT 32   // K / BK

__device__ __forceinline__ void gload_lds16(const void* g, void* l) {
    // 16B-per-lane async global->LDS. LDS dest must be wave-uniform base + lane*16.
    __builtin_amdgcn_global_load_lds((__attribute__((address_space(1))) void*)g,
                                     (__attribute__((address_space(3))) void*)l,
                                     16, 0, 0);
}

// fp32 -> bf16 bits, round-to-nearest-even (finite inputs only).
__device__ __forceinline__ unsigned short f2bf_bits(float f) {
    unsigned int u = __float_as_uint(f);
    u += 0x7FFFu + ((u >> 16) & 1u);
    return (unsigned short)(u >> 16);
}

// ---------------------------------------------------------------------------
// Fused aux kernel (R7 version).
//   blocks [0, 8192):      Xbf = bf16(x)
//   blocks [8192, 10240):  Weff = bf16(W + scale*B@A)
// ---------------------------------------------------------------------------
__global__ __launch_bounds__(256)
void aux_kernel(const float* __restrict__ x, unsigned short* __restrict__ Xbf,
                const float* __restrict__ W, const float* __restrict__ A,
                const float* __restrict__ Bm, const float* __restrict__ scale_p,
                unsigned short* __restrict__ Weff)
{
    const int K = 2048, R = 16;
    int bid = blockIdx.x;
    if (bid < 8192) {
        size_t i = ((size_t)bid * 256 + threadIdx.x) * 8;
        float4 a = *reinterpret_cast<const float4*>(x + i);
        float4 b = *reinterpret_cast<const float4*>(x + i + 4);
        ushort8 o;
        o[0] = f2bf_bits(a.x); o[1] = f2bf_bits(a.y);
        o[2] = f2bf_bits(a.z); o[3] = f2bf_bits(a.w);
        o[4] = f2bf_bits(b.x); o[5] = f2bf_bits(b.y);
        o[6] = f2bf_bits(b.z); o[7] = f2bf_bits(b.w);
        *reinterpret_cast<ushort8*>(Xbf + i) = o;
    } else {
        int t  = (bid - 8192) * 256 + threadIdx.x;
        int n  = t >> 8;
        int k8 = (t & 255) << 3;

        float s = *scale_p;
        float br[16];
#pragma unroll
        for (int r = 0; r < R; ++r)
            br[r] = s * Bm[n * R + r];

        float acc[8] = {0,0,0,0,0,0,0,0};
#pragma unroll
        for (int r = 0; r < R; ++r) {
            const float* ap = A + r * K + k8;
#pragma unroll
            for (int j = 0; j < 8; ++j)
                acc[j] += br[r] * ap[j];
        }

        const float* wp = W + (size_t)n * K + k8;
        ushort8 o;
#pragma unroll
        for (int j = 0; j < 8; ++j)
            o[j] = f2bf_bits(wp[j] + acc[j]);
        *reinterpret_cast<ushort8*>(Weff + (size_t)n * K + k8) = o;
    }
}

// ---------------------------------------------------------------------------
// GEMM: out[M,N] (fp32) = Xbf[M,K] @ Weffbf[N,K]^T + bias (fp32)
//
// LDS regions (16 KB each, 128 KiB total), all staged by global_load_lds
// (linear dest, pre-swizzled source):
//   Sa[buf][mh]: A M-half [wrH(2)][64 r][64 c bf16], rows bm+wrH*128+mh*64+r.
//   Sb[buf][nh]: B N-half [wcH(4)][32 r][64 c],      rows bn+wcH*64+nh*32+r.
// Swizzle involution (both sides): 16B slot s -> s ^ (row&7). Measured 0
// bank conflicts (R6/R7).
//
// MFMA 32x32x16 fragment addressing: lane holds row l31=lane&31, k-window
// (lane>>5)*8; per phase a (mh,nh) quadrant = 2 m-blocks x 1 n-block x 4 ks.
// Read cadence per tile (Gray m0n0, m0n1, m1n1, m1n0): 12 / 4 / 8 / 0 b128.
// bqa (nh0) stays live P1->P4; bqb (nh1) P2->P3; af overwritten per mh.
//
// Staging slots + vmcnt: R7 VERBATIM (hand-verified, HW-passing):
//   P1: B-gl Sb[1][0]<-t1   P2: A-gl Sa[1][1]<-t1
//   P3: A-gl Sa[0][0]<-t2   P4: B-gl Sb[0][1]<-t2  + vmcnt(4)
//   P5: B-gl Sb[0][0]<-t2   P6: A-gl Sa[0][1]<-t2
//   P7: A-gl Sa[1][0]<-t3   P8: B-gl Sb[1][1]<-t3  + vmcnt(4)
// ---------------------------------------------------------------------------
#define BAR()       __builtin_amdgcn_s_barrier()
#define WAIT_LGKM() asm volatile("s_waitcnt lgkmcnt(0)" ::: "memory")
#define WAIT_VM4()  asm volatile("s_waitcnt vmcnt(4)" ::: "memory")
#define WAIT_VM0()  asm volatile("s_waitcnt vmcnt(0)" ::: "memory")

#define STAGE_A(buf, mh, kt) do {                                             \
    gload_lds16(gA0 + (size_t)(mh) * 64 * 2048 + (kt) * 64, &Sa[buf][mh][c0 * 8]); \
    gload_lds16(gA1 + (size_t)(mh) * 64 * 2048 + (kt) * 64, &Sa[buf][mh][c1 * 8]); \
} while (0)

#define STAGE_B(buf, nh, kt) do {                                             \
    gload_lds16(gB0 + (size_t)(nh) * 32 * 2048 + (kt) * 64, &Sb[buf][nh][c0 * 8]); \
    gload_lds16(gB1 + (size_t)(nh) * 32 * 2048 + (kt) * 64, &Sb[buf][nh][c1 * 8]); \
} while (0)

// af[mb][ks] <- A quadrant (mh): rows wr*64? no: region-local mb*32+l31,
// wrH selected by wr. 8 x ds_read_b128.
#define READ_A(buf, mh) do {                                                  \
    const unsigned short* ra = &Sa[buf][mh][(wr * 64 + l31) * 64];            \
    _Pragma("unroll")                                                         \
    for (int ks = 0; ks < 4; ++ks) {                                          \
        af[0][ks] = *reinterpret_cast<const bf16x8*>(ra + swzk[ks]);          \
        af[1][ks] = *reinterpret_cast<const bf16x8*>(ra + 2048 + swzk[ks]);   \
    }                                                                         \
} while (0)

// BQ[ks] <- B n-block (nh). 4 x ds_read_b128.
#define READ_B(buf, nh, BQ) do {                                              \
    const unsigned short* rb = &Sb[buf][nh][(wc * 32 + l31) * 64];            \
    _Pragma("unroll")                                                         \
    for (int ks = 0; ks < 4; ++ks)                                            \
        BQ[ks] = *reinterpret_cast<const bf16x8*>(rb + swzk[ks]);             \
} while (0)

// 8 x mfma_f32_32x32x16_bf16; ks outer / mb inner alternates the two
// dependent chains so each gets 2-slot spacing.
#define MFMAQ(mh, nh, BQ) do {                                                \
    __builtin_amdgcn_s_setprio(1);                                            \
    _Pragma("unroll")                                                         \
    for (int ks = 0; ks < 4; ++ks) {                                          \
        acc[(mh)*2+0][nh] = __builtin_amdgcn_mfma_f32_32x32x16_bf16(          \
            af[0][ks], BQ[ks], acc[(mh)*2+0][nh], 0, 0, 0);                   \
        acc[(mh)*2+1][nh] = __builtin_amdgcn_mfma_f32_32x32x16_bf16(          \
            af[1][ks], BQ[ks], acc[(mh)*2+1][nh], 0, 0, 0);                   \
    }                                                                         \
    __builtin_amdgcn_s_setprio(0);                                            \
} while (0)

__global__ __launch_bounds__(512)
void gemm_bias_kernel(const unsigned short* __restrict__ X,
                      const unsigned short* __restrict__ Wt,
                      const float* __restrict__ bias,
                      float* __restrict__ out)
{
    const int N = 2048, K = 2048;

    __shared__ alignas(16) unsigned short Sa[2][2][8192];   // 64 KB
    __shared__ alignas(16) unsigned short Sb[2][2][8192];   // 64 KB

    const int tid  = threadIdx.x;
    const int wave = tid >> 6;
    const int lane = tid & 63;
    const int l31  = lane & 31;
    const int kg   = lane >> 5;   // k-window selector for 32x32 fragments
    const int l7   = lane & 7;
    const int wr   = wave >> 2;   // 0..1  (M split)
    const int wc   = wave & 3;    // 0..3  (N split)

    // XCD-rectangle swizzle (bijective, 256 % 8 == 0).
    const int id  = blockIdx.x;            // 0..255
    const int xcd = id & 7;
    const int sg  = id >> 3;               // 0..31
    const int bm  = (xcd * 4 + (sg & 3)) * BM;
    const int bn  = (sg >> 2) * BN;

    // --- A staging (global_load_lds). Granule c: wrH=c>>9, row=(c>>3)&63,
    // slot=c&7; LDS dest linear; global col pre-swizzled (slot ^ row&7).
    const int c0 = tid, c1 = tid + 512;
    const int ar0 = (c0 >> 3) & 63, as0 = c0 & 7;
    const int ar1 = (c1 >> 3) & 63, as1 = c1 & 7;
    const unsigned short* gA0 = X + (size_t)(bm + (c0 >> 9) * 128 + ar0) * K
                                  + ((as0 ^ (ar0 & 7)) << 3);
    const unsigned short* gA1 = X + (size_t)(bm + (c1 >> 9) * 128 + ar1) * K
                                  + ((as1 ^ (ar1 & 7)) << 3);
    // --- B staging. Granule c: wcH=c>>8, row=(c>>3)&31, slot=c&7.
    const int br0 = (c0 >> 3) & 31, br1 = (c1 >> 3) & 31;
    const unsigned short* gB0 = Wt + (size_t)(bn + (c0 >> 8) * 64 + br0) * K
                                   + ((as0 ^ (br0 & 7)) << 3);
    const unsigned short* gB1 = Wt + (size_t)(bn + (c1 >> 8) * 64 + br1) * K
                                   + ((as1 ^ (br1 & 7)) << 3);

    // ds_read swizzle: logical 16B granule g = ks*2 + kg, phys = g ^ (row&7),
    // row&7 == l7 for every fragment row (region rows are l31 + mult of 32).
    const int swzk[4] = { ((0 + kg) ^ l7) << 3, ((2 + kg) ^ l7) << 3,
                          ((4 + kg) ^ l7) << 3, ((6 + kg) ^ l7) << 3 };

    floatx16 acc[4][2] = {};   // [m-block 0..3][n-block 0..1]
    bf16x8 af[2][4];           // [mb within quadrant][ks]
    bf16x8 bqa[4], bqb[4];     // nh0 (lives P1->P4), nh1 (P2->P3)

    // Prologue (R7 verbatim): tile0 all 4 half-tiles + tile1 {A-m0, B-n1}.
    STAGE_A(0, 0, 0);
    STAGE_B(0, 1, 0);
    STAGE_B(0, 0, 0);
    STAGE_A(0, 1, 0);
    STAGE_A(1, 0, 1);
    STAGE_B(1, 1, 1);
    WAIT_VM4(); BAR();

#pragma unroll 1
    for (int tt = 0; tt < NT; tt += 2) {
        const int t1 = tt + 1;
        const int t2 = (tt + 2 < NT) ? tt + 2 : NT - 1;   // clamped tail
        const int t3 = (tt + 3 < NT) ? tt + 3 : NT - 1;   // (dead regions)

        // ---- tile t (buf0) ----
        // P1 (m0,n0)
        READ_A(0, 0); READ_B(0, 0, bqa);
        STAGE_B(1, 0, t1);
        BAR(); WAIT_LGKM(); MFMAQ(0, 0, bqa); BAR();
        // P2 (m0,n1)
        READ_B(0, 1, bqb);
        STAGE_A(1, 1, t1);
        BAR(); WAIT_LGKM(); MFMAQ(0, 1, bqb); BAR();
        // P3 (m1,n1)
        READ_A(0, 1);
        STAGE_A(0, 0, t2);
        BAR(); WAIT_LGKM(); MFMAQ(1, 1, bqb); BAR();
        // P4 (m1,n0) — zero ds_reads (bqa still live)
        STAGE_B(0, 1, t2);
        BAR(); WAIT_LGKM(); MFMAQ(1, 0, bqa); WAIT_VM4(); BAR();

        // ---- tile t+1 (buf1) ----
        // P5 (m0,n0)
        READ_A(1, 0); READ_B(1, 0, bqa);
        STAGE_B(0, 0, t2);
        BAR(); WAIT_LGKM(); MFMAQ(0, 0, bqa); BAR();
        // P6 (m0,n1)
        READ_B(1, 1, bqb);
        STAGE_A(0, 1, t2);
        BAR(); WAIT_LGKM(); MFMAQ(0, 1, bqb); BAR();
        // P7 (m1,n1)
        READ_A(1, 1);
        STAGE_A(1, 0, t3);
        BAR(); WAIT_LGKM(); MFMAQ(1, 1, bqb); BAR();
        // P8 (m1,n0) — zero ds_reads
        STAGE_B(1, 1, t3);
        BAR(); WAIT_LGKM(); MFMAQ(1, 0, bqa); WAIT_VM4(); BAR();
    }
    WAIT_VM0();   // drain tail stages before epilogue stores

    // Epilogue. 32x32 C/D layout (m74/m101): col = lane&31,
    // row = (reg&3) + 8*(reg>>2) + 4*(lane>>5), reg in [0,16).
    const float bsv0 = bias[bn + wc * 64 + l31];
    const float bsv1 = bias[bn + wc * 64 + 32 + l31];
    const size_t cb  = (size_t)bn + wc * 64 + l31;
#pragma unroll
    for (int mb = 0; mb < 4; ++mb) {
#pragma unroll
        for (int r = 0; r < 16; ++r) {
            size_t rowoff = (size_t)(bm + wr * 128 + mb * 32
                                     + (r & 3) + ((r >> 2) << 3) + (kg << 2)) * N;
            out[rowoff + cb]      = acc[mb][0][r] + bsv0;
            out[rowoff + cb + 32] = acc[mb][1][r] + bsv1;
        }
    }
}

extern "C" void kernel_launch(void* const* d_in, const int* in_sizes, int n_in,
                              void* d_out, int out_size, void* d_ws, size_t ws_size,
                              hipStream_t stream)
{
    const float* x  = (const float*)d_in[0];
    const float* W  = (const float*)d_in[1];
    const float* b  = (const float*)d_in[2];
    const float* A  = (const float*)d_in[3];
    const float* Bm = (const float*)d_in[4];
    const float* sc = (const float*)d_in[5];
    float* out = (float*)d_out;

    const size_t M = 8192, N = 2048, K = 2048;

    unsigned short* Xbf  = (unsigned short*)d_ws;                 // 32 MB
    unsigned short* Weff = (unsigned short*)d_ws + M * K;         // + 8 MB

    // 1) fused: Xbf = bf16(x); Weff = bf16(W + scale * B@A)
    aux_kernel<<<dim3((M * K + N * K) / 8 / 256), dim3(256), 0, stream>>>(
        x, Xbf, W, A, Bm, sc, Weff);

    // 2) out = Xbf @ Weff^T + b  (fp32 out), 256 blocks = 256 CUs, no tails
    gemm_bias_kernel<<<dim3((M / BM) * (N / BN)), dim3(512), 0, stream>>>(
        Xbf, Weff, b, out);
}

// Round 6
// 209.509 us; speedup vs baseline: 1.1348x; 1.0040x over previous
//
#include <hip/hip_runtime.h>
#include <hip/hip_bf16.h>
#include <cstdint>

// Problem: out = x @ (W + scale*B@A)^T + b
//   x[4,2048,2048] -> X[M=8192, K=2048],  W[N=2048, K=2048], b[N],
//   A[R=16, K], B[N, R=16], scale scalar.  ALL I/O IS FLOAT32.
// R7:  16x16 MFMA, m201 cadence -> 75.4us GEMM, 207.5 total.
// R10: 32x32x16 MFMA (2382 vs 2075 TF ubench) + P4/P8 zero-ds_read ->
//      78.3us, PASSED but SQ_LDS_BANK_CONFLICT 0 -> 6.29M = exactly 4
//      extra cycles on EVERY b128 read: 32x32 fragment rows span 32 with
//      granule varying only in lane>>5, so lanes {l,l+8,l+16,l+24} (same
//      l7) hit the same bank-word = 4-way conflict. Swizzle only mixed
//      row&7.
// R11: extend involution to f(row) = (row&7) ^ ((row>>3)&3) on BOTH sides
//      (pre-swizzled gload source + ds_read). At fixed l7 the 8 lanes
//      (kg, l31>>3) now map 2-per-granule = R7's measured-free density.
//      Everything else R10-verbatim.

typedef __bf16 bf16x8 __attribute__((ext_vector_type(8)));
typedef float floatx16 __attribute__((ext_vector_type(16)));
typedef unsigned short ushort8 __attribute__((ext_vector_type(8)));

#define BM 256
#define BN 256
#define BK 64
#define NT 32   // K / BK

__device__ __forceinline__ void gload_lds16(const void* g, void* l) {
    // 16B-per-lane async global->LDS. LDS dest must be wave-uniform base + lane*16.
    __builtin_amdgcn_global_load_lds((__attribute__((address_space(1))) void*)g,
                                     (__attribute__((address_space(3))) void*)l,
                                     16, 0, 0);
}

// fp32 -> bf16 bits, round-to-nearest-even (finite inputs only).
__device__ __forceinline__ unsigned short f2bf_bits(float f) {
    unsigned int u = __float_as_uint(f);
    u += 0x7FFFu + ((u >> 16) & 1u);
    return (unsigned short)(u >> 16);
}

// ---------------------------------------------------------------------------
// Fused aux kernel.
//   blocks [0, 8192):      Xbf = bf16(x)
//   blocks [8192, 10240):  Weff = bf16(W + scale*B@A)
// ---------------------------------------------------------------------------
__global__ __launch_bounds__(256)
void aux_kernel(const float* __restrict__ x, unsigned short* __restrict__ Xbf,
                const float* __restrict__ W, const float* __restrict__ A,
                const float* __restrict__ Bm, const float* __restrict__ scale_p,
                unsigned short* __restrict__ Weff)
{
    const int K = 2048, R = 16;
    int bid = blockIdx.x;
    if (bid < 8192) {
        size_t i = ((size_t)bid * 256 + threadIdx.x) * 8;
        float4 a = *reinterpret_cast<const float4*>(x + i);
        float4 b = *reinterpret_cast<const float4*>(x + i + 4);
        ushort8 o;
        o[0] = f2bf_bits(a.x); o[1] = f2bf_bits(a.y);
        o[2] = f2bf_bits(a.z); o[3] = f2bf_bits(a.w);
        o[4] = f2bf_bits(b.x); o[5] = f2bf_bits(b.y);
        o[6] = f2bf_bits(b.z); o[7] = f2bf_bits(b.w);
        *reinterpret_cast<ushort8*>(Xbf + i) = o;
    } else {
        int t  = (bid - 8192) * 256 + threadIdx.x;
        int n  = t >> 8;
        int k8 = (t & 255) << 3;

        float s = *scale_p;
        float br[16];
#pragma unroll
        for (int r = 0; r < R; ++r)
            br[r] = s * Bm[n * R + r];

        float acc[8] = {0,0,0,0,0,0,0,0};
#pragma unroll
        for (int r = 0; r < R; ++r) {
            const float* ap = A + r * K + k8;
#pragma unroll
            for (int j = 0; j < 8; ++j)
                acc[j] += br[r] * ap[j];
        }

        const float* wp = W + (size_t)n * K + k8;
        ushort8 o;
#pragma unroll
        for (int j = 0; j < 8; ++j)
            o[j] = f2bf_bits(wp[j] + acc[j]);
        *reinterpret_cast<ushort8*>(Weff + (size_t)n * K + k8) = o;
    }
}

// ---------------------------------------------------------------------------
// GEMM: out[M,N] (fp32) = Xbf[M,K] @ Weffbf[N,K]^T + bias (fp32)
//
// LDS regions (16 KB each, 128 KiB total), staged by global_load_lds
// (linear dest, pre-swizzled source):
//   Sa[buf][mh]: A M-half [wrH(2)][64 r][64 c bf16], rows bm+wrH*128+mh*64+r.
//   Sb[buf][nh]: B N-half [wcH(4)][32 r][64 c],      rows bn+wcH*64+nh*32+r.
// Swizzle involution (both sides): 16B slot s -> s ^ (r&7) ^ ((r>>3)&3).
// The ((r>>3)&3) term breaks R10's 4-way conflict (rows span 32 in the
// 32x32 read pattern); every bank-word is hit by exactly 2 lanes (free).
//
// MFMA 32x32x16: lane holds row l31=lane&31, k-window kg=(lane>>5)*8.
// Per phase a (mh,nh) quadrant = 2 m-blocks x 1 n-block x 4 ks = 8 MFMA.
// Read cadence per tile (Gray m0n0, m0n1, m1n1, m1n0): 12 / 4 / 8 / 0 b128.
// bqa (nh0) lives P1->P4; bqb (nh1) P2->P3.
//
// Staging slots + vmcnt: R7 VERBATIM (HW-passing):
//   P1: B-gl Sb[1][0]<-t1   P2: A-gl Sa[1][1]<-t1
//   P3: A-gl Sa[0][0]<-t2   P4: B-gl Sb[0][1]<-t2  + vmcnt(4)
//   P5: B-gl Sb[0][0]<-t2   P6: A-gl Sa[0][1]<-t2
//   P7: A-gl Sa[1][0]<-t3   P8: B-gl Sb[1][1]<-t3  + vmcnt(4)
// ---------------------------------------------------------------------------
#define BAR()       __builtin_amdgcn_s_barrier()
#define WAIT_LGKM() asm volatile("s_waitcnt lgkmcnt(0)" ::: "memory")
#define WAIT_VM4()  asm volatile("s_waitcnt vmcnt(4)" ::: "memory")
#define WAIT_VM0()  asm volatile("s_waitcnt vmcnt(0)" ::: "memory")

#define STAGE_A(buf, mh, kt) do {                                             \
    gload_lds16(gA0 + (size_t)(mh) * 64 * 2048 + (kt) * 64, &Sa[buf][mh][c0 * 8]); \
    gload_lds16(gA1 + (size_t)(mh) * 64 * 2048 + (kt) * 64, &Sa[buf][mh][c1 * 8]); \
} while (0)

#define STAGE_B(buf, nh, kt) do {                                             \
    gload_lds16(gB0 + (size_t)(nh) * 32 * 2048 + (kt) * 64, &Sb[buf][nh][c0 * 8]); \
    gload_lds16(gB1 + (size_t)(nh) * 32 * 2048 + (kt) * 64, &Sb[buf][nh][c1 * 8]); \
} while (0)

// af[mb][ks] <- A quadrant (mh). 8 x ds_read_b128.
#define READ_A(buf, mh) do {                                                  \
    const unsigned short* ra = &Sa[buf][mh][(wr * 64 + l31) * 64];            \
    _Pragma("unroll")                                                         \
    for (int ks = 0; ks < 4; ++ks) {                                          \
        af[0][ks] = *reinterpret_cast<const bf16x8*>(ra + swzk[ks]);          \
        af[1][ks] = *reinterpret_cast<const bf16x8*>(ra + 2048 + swzk[ks]);   \
    }                                                                         \
} while (0)

// BQ[ks] <- B n-block (nh). 4 x ds_read_b128.
#define READ_B(buf, nh, BQ) do {                                              \
    const unsigned short* rb = &Sb[buf][nh][(wc * 32 + l31) * 64];            \
    _Pragma("unroll")                                                         \
    for (int ks = 0; ks < 4; ++ks)                                            \
        BQ[ks] = *reinterpret_cast<const bf16x8*>(rb + swzk[ks]);             \
} while (0)

// 8 x mfma_f32_32x32x16_bf16; ks outer / mb inner gives each dependent
// accumulator chain 2-slot spacing.
#define MFMAQ(mh, nh, BQ) do {                                                \
    __builtin_amdgcn_s_setprio(1);                                            \
    _Pragma("unroll")                                                         \
    for (int ks = 0; ks < 4; ++ks) {                                          \
        acc[(mh)*2+0][nh] = __builtin_amdgcn_mfma_f32_32x32x16_bf16(          \
            af[0][ks], BQ[ks], acc[(mh)*2+0][nh], 0, 0, 0);                   \
        acc[(mh)*2+1][nh] = __builtin_amdgcn_mfma_f32_32x32x16_bf16(          \
            af[1][ks], BQ[ks], acc[(mh)*2+1][nh], 0, 0, 0);                   \
    }                                                                         \
    __builtin_amdgcn_s_setprio(0);                                            \
} while (0)

__global__ __launch_bounds__(512)
void gemm_bias_kernel(const unsigned short* __restrict__ X,
                      const unsigned short* __restrict__ Wt,
                      const float* __restrict__ bias,
                      float* __restrict__ out)
{
    const int N = 2048, K = 2048;

    __shared__ alignas(16) unsigned short Sa[2][2][8192];   // 64 KB
    __shared__ alignas(16) unsigned short Sb[2][2][8192];   // 64 KB

    const int tid  = threadIdx.x;
    const int wave = tid >> 6;
    const int lane = tid & 63;
    const int l31  = lane & 31;
    const int kg   = lane >> 5;   // k-window selector for 32x32 fragments
    const int l7   = lane & 7;
    const int wr   = wave >> 2;   // 0..1  (M split)
    const int wc   = wave & 3;    // 0..3  (N split)

    // XCD-rectangle swizzle (bijective, 256 % 8 == 0).
    const int id  = blockIdx.x;            // 0..255
    const int xcd = id & 7;
    const int sg  = id >> 3;               // 0..31
    const int bm  = (xcd * 4 + (sg & 3)) * BM;
    const int bn  = (sg >> 2) * BN;

    // --- A staging (global_load_lds). Granule c: wrH=c>>9, row=(c>>3)&63,
    // slot=c&7; LDS dest linear; global col pre-swizzled with
    // f(r) = (r&7) ^ ((r>>3)&3).
    const int c0 = tid, c1 = tid + 512;
    const int ar0 = (c0 >> 3) & 63, as0 = c0 & 7;
    const int ar1 = (c1 >> 3) & 63, as1 = c1 & 7;
    const unsigned short* gA0 = X + (size_t)(bm + (c0 >> 9) * 128 + ar0) * K
                                  + ((as0 ^ (ar0 & 7) ^ ((ar0 >> 3) & 3)) << 3);
    const unsigned short* gA1 = X + (size_t)(bm + (c1 >> 9) * 128 + ar1) * K
                                  + ((as1 ^ (ar1 & 7) ^ ((ar1 >> 3) & 3)) << 3);
    // --- B staging. Granule c: wcH=c>>8, row=(c>>3)&31, slot=c&7.
    const int br0 = (c0 >> 3) & 31, br1 = (c1 >> 3) & 31;
    const unsigned short* gB0 = Wt + (size_t)(bn + (c0 >> 8) * 64 + br0) * K
                                   + ((as0 ^ (br0 & 7) ^ ((br0 >> 3) & 3)) << 3);
    const unsigned short* gB1 = Wt + (size_t)(bn + (c1 >> 8) * 64 + br1) * K
                                   + ((as1 ^ (br1 & 7) ^ ((br1 >> 3) & 3)) << 3);

    // ds_read swizzle: logical 16B granule g = ks*2 + kg, phys = g ^ f(row).
    // Fragment rows are l31 + {0,32,64,wc*32}: all offsets ==0 mod 32, so
    // f(row) = l7 ^ (l31>>3) for every read.
    const int fr   = l7 ^ (l31 >> 3);
    const int swzk[4] = { ((0 + kg) ^ fr) << 3, ((2 + kg) ^ fr) << 3,
                          ((4 + kg) ^ fr) << 3, ((6 + kg) ^ fr) << 3 };

    floatx16 acc[4][2] = {};   // [m-block 0..3][n-block 0..1]
    bf16x8 af[2][4];           // [mb within quadrant][ks]
    bf16x8 bqa[4], bqb[4];     // nh0 (lives P1->P4), nh1 (P2->P3)

    // Prologue (R7 verbatim): tile0 all 4 half-tiles + tile1 {A-m0, B-n1}.
    STAGE_A(0, 0, 0);
    STAGE_B(0, 1, 0);
    STAGE_B(0, 0, 0);
    STAGE_A(0, 1, 0);
    STAGE_A(1, 0, 1);
    STAGE_B(1, 1, 1);
    WAIT_VM4(); BAR();

#pragma unroll 1
    for (int tt = 0; tt < NT; tt += 2) {
        const int t1 = tt + 1;
        const int t2 = (tt + 2 < NT) ? tt + 2 : NT - 1;   // clamped tail
        const int t3 = (tt + 3 < NT) ? tt + 3 : NT - 1;   // (dead regions)

        // ---- tile t (buf0) ----
        // P1 (m0,n0)
        READ_A(0, 0); READ_B(0, 0, bqa);
        STAGE_B(1, 0, t1);
        BAR(); WAIT_LGKM(); MFMAQ(0, 0, bqa); BAR();
        // P2 (m0,n1)
        READ_B(0, 1, bqb);
        STAGE_A(1, 1, t1);
        BAR(); WAIT_LGKM(); MFMAQ(0, 1, bqb); BAR();
        // P3 (m1,n1)
        READ_A(0, 1);
        STAGE_A(0, 0, t2);
        BAR(); WAIT_LGKM(); MFMAQ(1, 1, bqb); BAR();
        // P4 (m1,n0) — zero ds_reads (bqa still live)
        STAGE_B(0, 1, t2);
        BAR(); WAIT_LGKM(); MFMAQ(1, 0, bqa); WAIT_VM4(); BAR();

        // ---- tile t+1 (buf1) ----
        // P5 (m0,n0)
        READ_A(1, 0); READ_B(1, 0, bqa);
        STAGE_B(0, 0, t2);
        BAR(); WAIT_LGKM(); MFMAQ(0, 0, bqa); BAR();
        // P6 (m0,n1)
        READ_B(1, 1, bqb);
        STAGE_A(0, 1, t2);
        BAR(); WAIT_LGKM(); MFMAQ(0, 1, bqb); BAR();
        // P7 (m1,n1)
        READ_A(1, 1);
        STAGE_A(1, 0, t3);
        BAR(); WAIT_LGKM(); MFMAQ(1, 1, bqb); BAR();
        // P8 (m1,n0) — zero ds_reads
        STAGE_B(1, 1, t3);
        BAR(); WAIT_LGKM(); MFMAQ(1, 0, bqa); WAIT_VM4(); BAR();
    }
    WAIT_VM0();   // drain tail stages before epilogue stores

    // Epilogue. 32x32 C/D layout (m74/m101): col = lane&31,
    // row = (reg&3) + 8*(reg>>2) + 4*(lane>>5), reg in [0,16).
    const float bsv0 = bias[bn + wc * 64 + l31];
    const float bsv1 = bias[bn + wc * 64 + 32 + l31];
    const size_t cb  = (size_t)bn + wc * 64 + l31;
#pragma unroll
    for (int mb = 0; mb < 4; ++mb) {
#pragma unroll
        for (int r = 0; r < 16; ++r) {
            size_t rowoff = (size_t)(bm + wr * 128 + mb * 32
                                     + (r & 3) + ((r >> 2) << 3) + (kg << 2)) * N;
            out[rowoff + cb]      = acc[mb][0][r] + bsv0;
            out[rowoff + cb + 32] = acc[mb][1][r] + bsv1;
        }
    }
}

extern "C" void kernel_launch(void* const* d_in, const int* in_sizes, int n_in,
                              void* d_out, int out_size, void* d_ws, size_t ws_size,
                              hipStream_t stream)
{
    const float* x  = (const float*)d_in[0];
    const float* W  = (const float*)d_in[1];
    const float* b  = (const float*)d_in[2];
    const float* A  = (const float*)d_in[3];
    const float* Bm = (const float*)d_in[4];
    const float* sc = (const float*)d_in[5];
    float* out = (float*)d_out;

    const size_t M = 8192, N = 2048, K = 2048;

    unsigned short* Xbf  = (unsigned short*)d_ws;                 // 32 MB
    unsigned short* Weff = (unsigned short*)d_ws + M * K;         // + 8 MB

    // 1) fused: Xbf = bf16(x); Weff = bf16(W + scale * B@A)
    aux_kernel<<<dim3((M * K + N * K) / 8 / 256), dim3(256), 0, stream>>>(
        x, Xbf, W, A, Bm, sc, Weff);

    // 2) out = Xbf @ Weff^T + b  (fp32 out), 256 blocks = 256 CUs, no tails
    gemm_bias_kernel<<<dim3((M / BM) * (N / BN)), dim3(512), 0, stream>>>(
        Xbf, Weff, b, out);
}